// Round 1
// baseline (574.092 us; speedup 1.0000x reference)
//
#include <hip/hip_runtime.h>
#include <hip/hip_fp16.h>
#include <cstdint>

// MultiHeadSelfAttention: N=2, S=4096, D=1024, H=16, hd=64, fp32 in/out.
// Pipeline: fp32->fp16 convert -> fused QKV GEMM (MFMA 16x16x32_f16, V stored
// transposed) -> flash attention (online softmax, 64x64 tiles).

typedef _Float16 f16;
typedef _Float16 f16x4_t __attribute__((ext_vector_type(4)));
typedef _Float16 f16x8_t __attribute__((ext_vector_type(8)));
typedef float f32x4_t __attribute__((ext_vector_type(4)));

#define NB 2
#define SEQ 4096
#define DM 1024
#define NH 16
#define HDIM 64

// XOR swizzle for tiles with 128-byte rows: spreads the 16B slot of each row
// across banks. Involution; leaves bits >=7 (row) and 0..3 (within 16B) alone.
__device__ __forceinline__ uint32_t swz128(uint32_t b) {
  return b ^ (((b >> 7) & 7u) << 4);
}

// Async global->LDS, 16B per lane. LDS dest must be wave-uniform base; HW
// writes base + lane*16. Global src is per-lane (pre-swizzled by caller).
__device__ __forceinline__ void gload_lds16(const void* g, void* l) {
  __builtin_amdgcn_global_load_lds(
      (const __attribute__((address_space(1))) uint32_t*)g,
      (__attribute__((address_space(3))) uint32_t*)l, 16, 0, 0);
}

__global__ void cvt_f32_to_f16(const float* __restrict__ in,
                               f16* __restrict__ out, int n4) {
  int idx = blockIdx.x * blockDim.x + threadIdx.x;
  int stride = blockDim.x * gridDim.x;
  for (int i = idx; i < n4; i += stride) {
    float4 v = reinterpret_cast<const float4*>(in)[i];
    f16x4_t h;
    h[0] = (f16)v.x; h[1] = (f16)v.y; h[2] = (f16)v.z; h[3] = (f16)v.w;
    reinterpret_cast<f16x4_t*>(out)[i] = h;
  }
}

// ---------------- fused QKV projection ----------------
// C[m, c] = sum_k xb[m,k] * wb[c,k],  m in [0,8192), c in [0,3072), k in [0,1024)
// wb rows 0..1023 = Wq, 1024..2047 = Wk, 2048..3071 = Wv (torch Linear: y = x W^T).
// Output routing: Q,K -> [n,h,s,d] fp16 ; V -> transposed [n,h,d,s] fp16.
#define PBM 128
#define PBN 128
#define PBK 64

__launch_bounds__(256)
__global__ void qkv_proj(const f16* __restrict__ xb, const f16* __restrict__ wb,
                         f16* __restrict__ Qg, f16* __restrict__ Kg,
                         f16* __restrict__ Vt) {
  __shared__ f16 As[PBM * PBK];  // 16KB, swizzled layout
  __shared__ f16 Bs[PBN * PBK];  // 16KB
  const int tid = threadIdx.x;
  const int wid = tid >> 6;
  const int lane = tid & 63;
  const int g = lane >> 4;
  const int r = lane & 15;
  const int mBase = blockIdx.x * PBM;
  const int nBase = blockIdx.y * PBN;
  const int wrow = wid >> 1, wcol = wid & 1;  // 2x2 waves, 64x64 each

  f32x4_t acc[4][4];
#pragma unroll
  for (int i = 0; i < 4; ++i)
#pragma unroll
    for (int j = 0; j < 4; ++j) acc[i][j] = (f32x4_t){0.f, 0.f, 0.f, 0.f};

  for (int kt = 0; kt < DM / PBK; ++kt) {
    // Stage A and B tiles (16KB each = 16 chunks of 1KB; 4 chunks per wave).
    // LDS is linear; the SOURCE address carries the swizzle (rule #21).
#pragma unroll
    for (int c4 = 0; c4 < 4; ++c4) {
      const int chunk = wid * 4 + c4;
      const uint32_t phys = chunk * 1024 + lane * 16;
      const uint32_t logb = swz128(phys);
      const uint32_t row = logb >> 7;     // tile row 0..127
      const uint32_t colb = logb & 127;   // byte within 128B row
      gload_lds16((const char*)xb + ((size_t)(mBase + row) * DM + kt * PBK) * 2 + colb,
                  (char*)As + (size_t)chunk * 1024);
      gload_lds16((const char*)wb + ((size_t)(nBase + row) * DM + kt * PBK) * 2 + colb,
                  (char*)Bs + (size_t)chunk * 1024);
    }
    __syncthreads();

#pragma unroll
    for (int kk = 0; kk < 2; ++kk) {  // two K=32 steps per BK=64
      f16x8_t a[4], b[4];
#pragma unroll
      for (int mi = 0; mi < 4; ++mi) {
        const uint32_t lb = ((uint32_t)(wrow * 64 + mi * 16 + r) << 7) + kk * 64 + g * 16;
        a[mi] = *reinterpret_cast<const f16x8_t*>((const char*)As + swz128(lb));
      }
#pragma unroll
      for (int ni = 0; ni < 4; ++ni) {
        const uint32_t lb = ((uint32_t)(wcol * 64 + ni * 16 + r) << 7) + kk * 64 + g * 16;
        b[ni] = *reinterpret_cast<const f16x8_t*>((const char*)Bs + swz128(lb));
      }
#pragma unroll
      for (int mi = 0; mi < 4; ++mi)
#pragma unroll
        for (int ni = 0; ni < 4; ++ni)
          acc[mi][ni] = __builtin_amdgcn_mfma_f32_16x16x32_f16(a[mi], b[ni],
                                                               acc[mi][ni], 0, 0, 0);
    }
    __syncthreads();
  }

  // Epilogue. Block's 128 cols lie in exactly one of Q/K/V (128 | 1024) ->
  // uniform branch. C/D layout: col = lane&15, row = g*4 + reg (verified m89).
  const int part = nBase >> 10;
#pragma unroll
  for (int mi = 0; mi < 4; ++mi) {
#pragma unroll
    for (int ni = 0; ni < 4; ++ni) {
      const int c = nBase + wcol * 64 + ni * 16 + r;
      const int hh = (c & 1023) >> 6;
      const int d = c & 63;
      const int m0 = mBase + wrow * 64 + mi * 16 + g * 4;  // token of reg 0
      const int n = m0 >> 12;
      const int s0 = m0 & 4095;
      if (part == 2) {
        // V transposed: 4 regs are 4 consecutive tokens -> one 8B store.
        f16x4_t v4;
#pragma unroll
        for (int q = 0; q < 4; ++q) v4[q] = (f16)acc[mi][ni][q];
        *reinterpret_cast<f16x4_t*>(
            Vt + ((size_t)((n * NH + hh) << 6) + d) * SEQ + s0) = v4;
      } else {
        f16* dst = (part == 0) ? Qg : Kg;
#pragma unroll
        for (int q = 0; q < 4; ++q)
          dst[((size_t)((n * NH + hh) * SEQ + s0 + q) << 6) + d] =
              (f16)acc[mi][ni][q];
      }
    }
  }
}

// ---------------- flash attention ----------------
// Per block: one (n,h), 64 q-rows (wave w owns rows w*16..w*16+15).
// KV tiles of 64; K and V^T staged to LDS with swizzle; online softmax.
__launch_bounds__(256)
__global__ void attn(const f16* __restrict__ Qg, const f16* __restrict__ Kg,
                     const f16* __restrict__ Vt, float* __restrict__ out) {
  __shared__ f16 Ks[64 * 64];    // 8KB swizzled
  __shared__ f16 Vs[64 * 64];    // 8KB swizzled (rows = d, cols = kv)
  __shared__ f16 Ps[64][72];     // P round-trip, +8 pad (144B rows, 16B aligned)
  const int tid = threadIdx.x;
  const int wid = tid >> 6, lane = tid & 63, g = lane >> 4, r = lane & 15;
  const int bq = blockIdx.x & 63;
  const int nh = blockIdx.x >> 6;  // n*16 + h

  const f16* Qb = Qg + (size_t)nh * SEQ * HDIM;
  const f16* Kb = Kg + (size_t)nh * SEQ * HDIM;
  const f16* Vb = Vt + (size_t)nh * HDIM * SEQ;

  // Q fragments in registers: A[i=qrow][k], lane holds row (lane&15), k = g*8..g*8+7 (+32*ks)
  f16x8_t aq[2];
  const int qrow = bq * 64 + wid * 16 + r;
#pragma unroll
  for (int ks = 0; ks < 2; ++ks)
    aq[ks] = *reinterpret_cast<const f16x8_t*>(Qb + (size_t)qrow * HDIM + ks * 32 + g * 8);

  f32x4_t o[4];
#pragma unroll
  for (int f = 0; f < 4; ++f) o[f] = (f32x4_t){0.f, 0.f, 0.f, 0.f};
  float m_r[4], l_r[4];
#pragma unroll
  for (int i = 0; i < 4; ++i) { m_r[i] = -1e30f; l_r[i] = 0.f; }

  for (int t = 0; t < SEQ / 64; ++t) {
    // Stage K tile (contiguous 8KB in Kg) and V^T tile (64 rows x 128B, row
    // stride SEQ*2). 2 chunks of 1KB per wave for each.
#pragma unroll
    for (int p = 0; p < 2; ++p) {
      const int chunk = wid * 2 + p;
      const uint32_t phys = chunk * 1024 + lane * 16;
      const uint32_t logb = swz128(phys);
      gload_lds16((const char*)(Kb + (size_t)t * 64 * HDIM) + logb,
                  (char*)Ks + chunk * 1024);
      const uint32_t row = logb >> 7, colb = logb & 127;
      gload_lds16((const char*)Vb + (size_t)row * (SEQ * 2) + (size_t)t * 128 + colb,
                  (char*)Vs + chunk * 1024);
    }
    __syncthreads();

    // S = Q K^T  (raw scores; scale by 1/8 after, as in reference)
    f32x4_t sa[4];
#pragma unroll
    for (int f = 0; f < 4; ++f) sa[f] = (f32x4_t){0.f, 0.f, 0.f, 0.f};
#pragma unroll
    for (int f = 0; f < 4; ++f) {
#pragma unroll
      for (int ks = 0; ks < 2; ++ks) {
        const uint32_t lb = ((uint32_t)(f * 16 + r) << 7) + ks * 64 + g * 16;
        const f16x8_t bk =
            *reinterpret_cast<const f16x8_t*>((const char*)Ks + swz128(lb));
        sa[f] = __builtin_amdgcn_mfma_f32_16x16x32_f16(aq[ks], bk, sa[f], 0, 0, 0);
      }
    }

#pragma unroll
    for (int f = 0; f < 4; ++f) sa[f] *= 0.125f;

    // Online softmax. Lane holds rows g*4+i (i=0..3), cols f*16+r. The 16
    // lanes sharing g hold the same 4 rows -> shfl_xor 1,2,4,8 row-reduce.
    float scl[4];
#pragma unroll
    for (int i = 0; i < 4; ++i) {
      float mx = fmaxf(fmaxf(sa[0][i], sa[1][i]), fmaxf(sa[2][i], sa[3][i]));
#pragma unroll
      for (int off = 1; off < 16; off <<= 1) mx = fmaxf(mx, __shfl_xor(mx, off, 64));
      const float mnew = fmaxf(m_r[i], mx);
      const float sc = __expf(m_r[i] - mnew);
      float rs = 0.f;
#pragma unroll
      for (int f = 0; f < 4; ++f) {
        sa[f][i] = __expf(sa[f][i] - mnew);
        rs += sa[f][i];
      }
#pragma unroll
      for (int off = 1; off < 16; off <<= 1) rs += __shfl_xor(rs, off, 64);
      l_r[i] = l_r[i] * sc + rs;
      m_r[i] = mnew;
      scl[i] = sc;
    }
#pragma unroll
    for (int f = 0; f < 4; ++f)
#pragma unroll
      for (int i = 0; i < 4; ++i) o[f][i] *= scl[i];

    // P -> LDS (rows wid*16..wid*16+15 are wave-private: no barrier needed).
#pragma unroll
    for (int f = 0; f < 4; ++f)
#pragma unroll
      for (int i = 0; i < 4; ++i)
        Ps[wid * 16 + g * 4 + i][f * 16 + r] = (f16)sa[f][i];

    // PV: A = P[q][kv] (16B contiguous reads, 2-way free on pad-72 rows),
    //     B^T = V^T rows from swizzled Vs.
    f16x8_t ap[2];
#pragma unroll
    for (int ks = 0; ks < 2; ++ks)
      ap[ks] = *reinterpret_cast<const f16x8_t*>(&Ps[wid * 16 + r][ks * 32 + g * 8]);
#pragma unroll
    for (int f = 0; f < 4; ++f) {
#pragma unroll
      for (int ks = 0; ks < 2; ++ks) {
        const uint32_t lb = ((uint32_t)(f * 16 + r) << 7) + ks * 64 + g * 16;
        const f16x8_t bv =
            *reinterpret_cast<const f16x8_t*>((const char*)Vs + swz128(lb));
        o[f] = __builtin_amdgcn_mfma_f32_16x16x32_f16(ap[ks], bv, o[f], 0, 0, 0);
      }
    }
    __syncthreads();
  }

  // Normalize and write out[n, s, h*64 + d] fp32.
  const int n = nh >> 4, h = nh & 15;
#pragma unroll
  for (int f = 0; f < 4; ++f) {
#pragma unroll
    for (int i = 0; i < 4; ++i) {
      const int s = bq * 64 + wid * 16 + g * 4 + i;
      const int d = f * 16 + r;
      out[(size_t)(n * SEQ + s) * DM + h * 64 + d] = o[f][i] / l_r[i];
    }
  }
}

extern "C" void kernel_launch(void* const* d_in, const int* in_sizes, int n_in,
                              void* d_out, int out_size, void* d_ws, size_t ws_size,
                              hipStream_t stream) {
  const float* x  = (const float*)d_in[0];
  const float* Wq = (const float*)d_in[1];
  const float* Wk = (const float*)d_in[2];
  const float* Wv = (const float*)d_in[3];
  float* out = (float*)d_out;

  // Workspace layout (bytes): xb 16MB | wb 6MB | Qg 16MB | Kg 16MB | Vt 16MB = 70MB
  char* ws = (char*)d_ws;
  f16* xb = (f16*)(ws + 0);
  f16* wb = (f16*)(ws + 16777216);
  f16* Qg = (f16*)(ws + 23068672);
  f16* Kg = (f16*)(ws + 39845888);
  f16* Vt = (f16*)(ws + 56623104);

  cvt_f32_to_f16<<<2048, 256, 0, stream>>>(x, xb, NB * SEQ * DM / 4);
  cvt_f32_to_f16<<<1024, 256, 0, stream>>>(Wq, wb, DM * DM / 4);
  cvt_f32_to_f16<<<1024, 256, 0, stream>>>(Wk, wb + DM * DM, DM * DM / 4);
  cvt_f32_to_f16<<<1024, 256, 0, stream>>>(Wv, wb + 2 * DM * DM, DM * DM / 4);

  dim3 pgrid(NB * SEQ / PBM, (3 * DM) / PBN);  // 64 x 24
  qkv_proj<<<pgrid, 256, 0, stream>>>(xb, wb, Qg, Kg, Vt);

  attn<<<NB * NH * (SEQ / 64), 256, 0, stream>>>(Qg, Kg, Vt, out);
}

// Round 2
// 342.542 us; speedup vs baseline: 1.6760x; 1.6760x over previous
//
#include <hip/hip_runtime.h>
#include <hip/hip_fp16.h>
#include <cstdint>

// MultiHeadSelfAttention: N=2, S=4096, D=1024, H=16, hd=64, fp32 in/out.
// fp32->fp16 convert -> fused QKV GEMM (V stored transposed) ->
// flash attention (32x32 MFMA, swapped QK^T & PV, in-register softmax,
// permlane P routing, defer-max, double-buffered K/V staging).

typedef _Float16 f16;
typedef _Float16 f16x4_t __attribute__((ext_vector_type(4)));
typedef _Float16 f16x8_t __attribute__((ext_vector_type(8)));
typedef float f32x4_t __attribute__((ext_vector_type(4)));
typedef float f32x16_t __attribute__((ext_vector_type(16)));
typedef int i32x2_t __attribute__((ext_vector_type(2)));
typedef int i32x4_t __attribute__((ext_vector_type(4)));
typedef uint32_t u32;

#define NB 2
#define SEQ 4096
#define DM 1024
#define NH 16
#define HDIM 64

// XOR swizzle for 128-byte logical rows (proj tiles).
__device__ __forceinline__ u32 swz128(u32 b) {
  return b ^ (((b >> 7) & 7u) << 4);
}
// XOR swizzle for 256-byte logical rows (attn K/V tiles): 16 slots of 16B.
__device__ __forceinline__ u32 swz256(u32 b) {
  return b ^ (((b >> 8) & 15u) << 4);
}

__device__ __forceinline__ void gload_lds16(const void* g, void* l) {
  __builtin_amdgcn_global_load_lds(
      (const __attribute__((address_space(1))) uint32_t*)g,
      (__attribute__((address_space(3))) uint32_t*)l, 16, 0, 0);
}

__global__ void cvt_f32_to_f16(const float* __restrict__ in,
                               f16* __restrict__ out, int n4) {
  int idx = blockIdx.x * blockDim.x + threadIdx.x;
  int stride = blockDim.x * gridDim.x;
  for (int i = idx; i < n4; i += stride) {
    float4 v = reinterpret_cast<const float4*>(in)[i];
    f16x4_t h;
    h[0] = (f16)v.x; h[1] = (f16)v.y; h[2] = (f16)v.z; h[3] = (f16)v.w;
    reinterpret_cast<f16x4_t*>(out)[i] = h;
  }
}

// Fused convert of the three 1024x1024 weight matrices (one launch).
__global__ void cvt_w3(const float* __restrict__ a, const float* __restrict__ b,
                       const float* __restrict__ c, f16* __restrict__ outw) {
  const int i = blockIdx.x * blockDim.x + threadIdx.x;  // 0..262143
  const int n4 = DM * DM / 4;
  const float4 va = reinterpret_cast<const float4*>(a)[i];
  const float4 vb = reinterpret_cast<const float4*>(b)[i];
  const float4 vc = reinterpret_cast<const float4*>(c)[i];
  f16x4_t ha, hb, hc;
  ha[0]=(f16)va.x; ha[1]=(f16)va.y; ha[2]=(f16)va.z; ha[3]=(f16)va.w;
  hb[0]=(f16)vb.x; hb[1]=(f16)vb.y; hb[2]=(f16)vb.z; hb[3]=(f16)vb.w;
  hc[0]=(f16)vc.x; hc[1]=(f16)vc.y; hc[2]=(f16)vc.z; hc[3]=(f16)vc.w;
  reinterpret_cast<f16x4_t*>(outw)[i] = ha;
  reinterpret_cast<f16x4_t*>(outw)[n4 + i] = hb;
  reinterpret_cast<f16x4_t*>(outw)[2 * n4 + i] = hc;
}

// ---------------- fused QKV projection (unchanged, proven round 1) ----------
#define PBM 128
#define PBN 128
#define PBK 64

__launch_bounds__(256)
__global__ void qkv_proj(const f16* __restrict__ xb, const f16* __restrict__ wb,
                         f16* __restrict__ Qg, f16* __restrict__ Kg,
                         f16* __restrict__ Vt) {
  __shared__ f16 As[PBM * PBK];
  __shared__ f16 Bs[PBN * PBK];
  const int tid = threadIdx.x;
  const int wid = tid >> 6;
  const int lane = tid & 63;
  const int g = lane >> 4;
  const int r = lane & 15;
  const int mBase = blockIdx.x * PBM;
  const int nBase = blockIdx.y * PBN;
  const int wrow = wid >> 1, wcol = wid & 1;

  f32x4_t acc[4][4];
#pragma unroll
  for (int i = 0; i < 4; ++i)
#pragma unroll
    for (int j = 0; j < 4; ++j) acc[i][j] = (f32x4_t){0.f, 0.f, 0.f, 0.f};

  for (int kt = 0; kt < DM / PBK; ++kt) {
#pragma unroll
    for (int c4 = 0; c4 < 4; ++c4) {
      const int chunk = wid * 4 + c4;
      const u32 phys = chunk * 1024 + lane * 16;
      const u32 logb = swz128(phys);
      const u32 row = logb >> 7;
      const u32 colb = logb & 127;
      gload_lds16((const char*)xb + ((size_t)(mBase + row) * DM + kt * PBK) * 2 + colb,
                  (char*)As + (size_t)chunk * 1024);
      gload_lds16((const char*)wb + ((size_t)(nBase + row) * DM + kt * PBK) * 2 + colb,
                  (char*)Bs + (size_t)chunk * 1024);
    }
    __syncthreads();

#pragma unroll
    for (int kk = 0; kk < 2; ++kk) {
      f16x8_t a[4], b[4];
#pragma unroll
      for (int mi = 0; mi < 4; ++mi) {
        const u32 lb = ((u32)(wrow * 64 + mi * 16 + r) << 7) + kk * 64 + g * 16;
        a[mi] = *reinterpret_cast<const f16x8_t*>((const char*)As + swz128(lb));
      }
#pragma unroll
      for (int ni = 0; ni < 4; ++ni) {
        const u32 lb = ((u32)(wcol * 64 + ni * 16 + r) << 7) + kk * 64 + g * 16;
        b[ni] = *reinterpret_cast<const f16x8_t*>((const char*)Bs + swz128(lb));
      }
#pragma unroll
      for (int mi = 0; mi < 4; ++mi)
#pragma unroll
        for (int ni = 0; ni < 4; ++ni)
          acc[mi][ni] = __builtin_amdgcn_mfma_f32_16x16x32_f16(a[mi], b[ni],
                                                               acc[mi][ni], 0, 0, 0);
    }
    __syncthreads();
  }

  const int part = nBase >> 10;
#pragma unroll
  for (int mi = 0; mi < 4; ++mi) {
#pragma unroll
    for (int ni = 0; ni < 4; ++ni) {
      const int c = nBase + wcol * 64 + ni * 16 + r;
      const int hh = (c & 1023) >> 6;
      const int d = c & 63;
      const int m0 = mBase + wrow * 64 + mi * 16 + g * 4;
      const int n = m0 >> 12;
      const int s0 = m0 & 4095;
      if (part == 2) {
        f16x4_t v4;
#pragma unroll
        for (int q = 0; q < 4; ++q) v4[q] = (f16)acc[mi][ni][q];
        *reinterpret_cast<f16x4_t*>(
            Vt + ((size_t)((n * NH + hh) << 6) + d) * SEQ + s0) = v4;
      } else {
        f16* dst = (part == 0) ? Qg : Kg;
#pragma unroll
        for (int q = 0; q < 4; ++q)
          dst[((size_t)((n * NH + hh) * SEQ + s0 + q) << 6) + d] =
              (f16)acc[mi][ni][q];
      }
    }
  }
}

// ---------------- flash attention, 32x32 swapped-operand structure ----------
// Block: 4 waves x 64 q-rows = 256 q. KV tiles of 64. Lane owns q = qsub*32 +
// (lane&31); hi = lane>>5 splits k/d halves. S^T = mfma(K, Q); O^T =
// mfma(V^T, P^T): both keep col = q = lane&31 (C/D: col=lane&31,
// row=(reg&3)+8*(reg>>2)+4*hi — guide m74/m101).
// K LDS tile: logical byte (k&31)*256 + (k>>5)*128 + d*2 (32 rows x 256B).
// V^T tile:   logical byte (d&31)*256 + (d>>5)*128 + kloc*2.
// swz256 makes every ds_read_b128 2-way (free).

__device__ __forceinline__ void stage_kv(const f16* __restrict__ Kb,
                                         const f16* __restrict__ Vb, int t,
                                         f16* ksBuf, f16* vsBuf, int wid, int lane) {
#pragma unroll
  for (int c = 0; c < 2; ++c) {
    const int chunk = wid * 2 + c;               // 0..7
    const u32 phys = chunk * 1024 + lane * 16;
    const u32 lg = swz256(phys);
    const u32 row = lg >> 8;                     // 0..31
    const u32 within = lg & 255;
    const u32 half = within >> 7;
    const u32 col = (within & 127) >> 1;
    gload_lds16(Kb + ((size_t)(t * 64 + row + half * 32)) * HDIM + col,
                (char*)ksBuf + chunk * 1024);
    gload_lds16(Vb + (size_t)(row + 32 * half) * SEQ + t * 64 + col,
                (char*)vsBuf + chunk * 1024);
  }
}

__launch_bounds__(256, 2)
__global__ void attn(const f16* __restrict__ Qg, const f16* __restrict__ Kg,
                     const f16* __restrict__ Vt, float* __restrict__ out) {
  __shared__ f16 Ks[2][4096];  // 2 x 8KB
  __shared__ f16 Vs[2][4096];  // 2 x 8KB
  const int tid = threadIdx.x;
  const int wid = tid >> 6, lane = tid & 63;
  const int r5 = lane & 31, hi = lane >> 5;

  // XCD grouping: all 16 q-blocks of a head share one XCD's L2.
  const int bid = blockIdx.x;              // 0..511
  const int nh = (bid & 7) * 4 + ((bid >> 3) >> 4);
  const int qb = (bid >> 3) & 15;
  const int q0 = qb * 256 + wid * 64;

  const f16* Qb = Qg + (size_t)nh * SEQ * HDIM;
  const f16* Kb = Kg + (size_t)nh * SEQ * HDIM;
  const f16* Vb = Vt + (size_t)nh * HDIM * SEQ;

  // Q fragments (B-operand): lane q = q0+qsub*32+r5, d = cs*16 + hi*8 + e.
  f16x8_t qf[2][4];
#pragma unroll
  for (int qsub = 0; qsub < 2; ++qsub)
#pragma unroll
    for (int cs = 0; cs < 4; ++cs)
      qf[qsub][cs] = *reinterpret_cast<const f16x8_t*>(
          Qb + (size_t)(q0 + qsub * 32 + r5) * HDIM + cs * 16 + hi * 8);

  f32x16_t o_[2][2];  // [dsub][qsub]
#pragma unroll
  for (int a = 0; a < 2; ++a)
#pragma unroll
    for (int b = 0; b < 2; ++b) o_[a][b] = (f32x16_t)(0.f);
  float m_[2] = {-1e30f, -1e30f};
  float l_[2] = {0.f, 0.f};

  const float C_EXP = 0.125f;  // scores scaled by 1/sqrt(64) inside exp arg

  stage_kv(Kb, Vb, 0, Ks[0], Vs[0], wid, lane);
  __syncthreads();

  for (int t = 0; t < SEQ / 64; ++t) {
    const int buf = t & 1;
    if (t + 1 < SEQ / 64)
      stage_kv(Kb, Vb, t + 1, Ks[buf ^ 1], Vs[buf ^ 1], wid, lane);

    const char* ks = (const char*)Ks[buf];
    const char* vs = (const char*)Vs[buf];

    // S^T = K * Q^T  (A = K rows k, B = Q^T cols q)
    f32x16_t sacc[2][2];  // [qsub][ksub]
#pragma unroll
    for (int a = 0; a < 2; ++a)
#pragma unroll
      for (int b = 0; b < 2; ++b) sacc[a][b] = (f32x16_t)(0.f);
#pragma unroll
    for (int ksub = 0; ksub < 2; ++ksub)
#pragma unroll
      for (int cs = 0; cs < 4; ++cs) {
        const u32 lb = (u32)(r5 * 256 + ksub * 128 + cs * 32 + hi * 16);
        const f16x8_t kf = *reinterpret_cast<const f16x8_t*>(ks + swz256(lb));
#pragma unroll
        for (int qsub = 0; qsub < 2; ++qsub)
          sacc[qsub][ksub] = __builtin_amdgcn_mfma_f32_32x32x16_f16(
              kf, qf[qsub][cs], sacc[qsub][ksub], 0, 0, 0);
      }

    // Softmax (raw-score units; m tracked raw, THR = 64 raw = 8 scaled).
    f16x8_t pa[2][4];
#pragma unroll
    for (int qsub = 0; qsub < 2; ++qsub) {
      float pm = sacc[qsub][0][0];
#pragma unroll
      for (int e = 1; e < 16; ++e) pm = fmaxf(pm, sacc[qsub][0][e]);
#pragma unroll
      for (int e = 0; e < 16; ++e) pm = fmaxf(pm, sacc[qsub][1][e]);
      pm = fmaxf(pm, __shfl_xor(pm, 32, 64));
      if (!__all(pm - m_[qsub] <= 64.0f)) {
        const float mn = fmaxf(m_[qsub], pm);
        const float sc = __expf((m_[qsub] - mn) * C_EXP);
        l_[qsub] *= sc;
        o_[0][qsub] *= sc;
        o_[1][qsub] *= sc;
        m_[qsub] = mn;
      }
      float p[2][16];
      float rs = 0.f;
#pragma unroll
      for (int ksub = 0; ksub < 2; ++ksub)
#pragma unroll
        for (int e = 0; e < 16; ++e) {
          const float pe = __expf((sacc[qsub][ksub][e] - m_[qsub]) * C_EXP);
          p[ksub][e] = pe;
          rs += pe;
        }
      rs += __shfl_xor(rs, 32, 64);
      l_[qsub] += rs;

      // Pack P into A/B-frag layout: w[ksub][m] = pk(p[2m], p[2m+1]);
      // pa[ks] words t0,t0+2 from permlane32_swap(w[ks>>1][t0+4*(ks&1)], +2).
      int w_[2][8];
#pragma unroll
      for (int ksub = 0; ksub < 2; ++ksub)
#pragma unroll
        for (int mw = 0; mw < 8; ++mw)
          w_[ksub][mw] = __builtin_bit_cast(
              int, __builtin_amdgcn_cvt_pkrtz(p[ksub][2 * mw], p[ksub][2 * mw + 1]));
#pragma unroll
      for (int ks = 0; ks < 4; ++ks) {
        i32x4_t pw;
#pragma unroll
        for (int t0 = 0; t0 < 2; ++t0) {
          const int a = t0 + 4 * (ks & 1);
          const i32x2_t res = __builtin_amdgcn_permlane32_swap(
              w_[ks >> 1][a], w_[ks >> 1][a + 2], false, false);
          pw[t0] = res[0];
          pw[t0 + 2] = res[1];
        }
        pa[qsub][ks] = __builtin_bit_cast(f16x8_t, pw);
      }
    }

    // O^T += V^T * P^T  (A = V^T rows d, B = P^T cols q)
#pragma unroll
    for (int dsub = 0; dsub < 2; ++dsub)
#pragma unroll
      for (int ks = 0; ks < 4; ++ks) {
        const u32 lb = (u32)(r5 * 256 + dsub * 128 + ks * 32 + hi * 16);
        const f16x8_t vf = *reinterpret_cast<const f16x8_t*>(vs + swz256(lb));
#pragma unroll
        for (int qsub = 0; qsub < 2; ++qsub)
          o_[dsub][qsub] = __builtin_amdgcn_mfma_f32_32x32x16_f16(
              vf, pa[qsub][ks], o_[dsub][qsub], 0, 0, 0);
      }

    __syncthreads();
  }

  // Epilogue: O^T regs: col q = lane-owned, row d = dsub*32 + 8j + 4hi + i.
  const int n = nh >> 4, h = nh & 15;
#pragma unroll
  for (int qsub = 0; qsub < 2; ++qsub) {
    const float invl = 1.0f / l_[qsub];
    const int q = q0 + qsub * 32 + r5;
    float* orow = out + ((size_t)(n * SEQ + q)) * DM + h * 64;
#pragma unroll
    for (int dsub = 0; dsub < 2; ++dsub)
#pragma unroll
      for (int j = 0; j < 4; ++j) {
        float4 v4;
        v4.x = o_[dsub][qsub][4 * j + 0] * invl;
        v4.y = o_[dsub][qsub][4 * j + 1] * invl;
        v4.z = o_[dsub][qsub][4 * j + 2] * invl;
        v4.w = o_[dsub][qsub][4 * j + 3] * invl;
        *reinterpret_cast<float4*>(orow + dsub * 32 + 8 * j + 4 * hi) = v4;
      }
  }
}

extern "C" void kernel_launch(void* const* d_in, const int* in_sizes, int n_in,
                              void* d_out, int out_size, void* d_ws, size_t ws_size,
                              hipStream_t stream) {
  const float* x  = (const float*)d_in[0];
  const float* Wq = (const float*)d_in[1];
  const float* Wk = (const float*)d_in[2];
  const float* Wv = (const float*)d_in[3];
  float* out = (float*)d_out;

  char* ws = (char*)d_ws;
  f16* xb = (f16*)(ws + 0);
  f16* wb = (f16*)(ws + 16777216);
  f16* Qg = (f16*)(ws + 23068672);
  f16* Kg = (f16*)(ws + 39845888);
  f16* Vt = (f16*)(ws + 56623104);

  cvt_f32_to_f16<<<2048, 256, 0, stream>>>(x, xb, NB * SEQ * DM / 4);
  cvt_w3<<<DM * DM / 4 / 256, 256, 0, stream>>>(Wq, Wk, Wv, wb);

  dim3 pgrid(NB * SEQ / PBM, (3 * DM) / PBN);  // 64 x 24
  qkv_proj<<<pgrid, 256, 0, stream>>>(xb, wb, Qg, Kg, Vt);

  attn<<<NB * NH * (SEQ / 256), 256, 0, stream>>>(Qg, Kg, Vt, out);
}